// Round 4
// baseline (2157.567 us; speedup 1.0000x reference)
//
#include <hip/hip_runtime.h>
#include <hip/hip_bf16.h>
#include <cmath>

// SwinBlock fused kernel, round 6: BISECT. Round-3 structure (verified
// passing) with exactly ONE perf delta applied: weight staging via LDS
// (stage48/stage96 + sW) replaced by direct global-B MFMA reads
// (gemm_gB / gemm_gB_p48) whose read positions are element-identical to
// what the staging produced. Everything else is round 3 verbatim:
// scalar I/O, red-scratch LN1, separate sP, 16x48 MLP chunks, no XCD
// swizzle. Every intra-wave LDS write->read phase boundary keeps a real
// __syncthreads (37 total vs round 3's 145) -- no reliance on same-wave
// DS ordering or compiler alias behavior.
// LDS compacted to 60160 B (sW removed): sX[64][200]@0 | sQ[64][72]@25600 |
// sK[64][72]@34816 (later Hc) | sV[48][72]@44032 | sP[64][72]@50944 (=red).

using bf16 = __hip_bfloat16;
typedef __attribute__((ext_vector_type(8))) short short8;
typedef __attribute__((ext_vector_type(4))) float f32x4;

__device__ __forceinline__ float b2f(bf16 v) { return __bfloat162float(v); }
__device__ __forceinline__ bf16  f2b(float v) { return __float2bfloat16(v); }

template <bool ISBF>
__device__ __forceinline__ float gldf(const void* p, size_t i) {
  if constexpr (ISBF) return b2f(((const bf16*)p)[i]);
  else                return ((const float*)p)[i];
}
template <bool ISBF>
__device__ __forceinline__ void gst(void* p, size_t i, float v) {
  if constexpr (ISBF) ((bf16*)p)[i] = f2b(v);
  else                ((float*)p)[i] = v;
}

// ---------------- weight pre-transpose into workspace ----------------
// ws layout (bf16 elements): qkvT[576][192] @0 ; oT[192][192] @110592 ;
// m1T[768][192] @147456 ; m2T[192][768] @294912. Total 442368 elems.
template <bool ISBF>
__device__ __forceinline__ void transpose_body(
    const void* w_qkv, const void* w_o, const void* w_m1, const void* w_m2,
    bf16* ws, int id)
{
  if (id < 110592) {                       // qkv: src [192][576]
    int n = id / 192, k = id - n * 192;
    ws[id] = f2b(gldf<ISBF>(w_qkv, (size_t)k * 576 + n));
  } else if (id < 147456) {                // o: src [192][192]
    int l = id - 110592;
    int n = l / 192, k = l - n * 192;
    ws[id] = f2b(gldf<ISBF>(w_o, (size_t)k * 192 + n));
  } else if (id < 294912) {                // m1: src [192][768]
    int l = id - 147456;
    int n = l / 192, k = l - n * 192;
    ws[id] = f2b(gldf<ISBF>(w_m1, (size_t)k * 768 + n));
  } else {                                 // m2: src [768][192]
    int l = id - 294912;
    int n = l / 768, k = l - n * 768;
    ws[id] = f2b(gldf<ISBF>(w_m2, (size_t)k * 192 + n));
  }
}

__global__ __launch_bounds__(256) void transpose_weights(
    const void* w_qkv, const void* w_o, const void* w_m1, const void* w_m2,
    bf16* ws, int isbf)
{
  int id = blockIdx.x * 256 + threadIdx.x;
  if (id >= 442368) return;
  if (isbf) transpose_body<true >(w_qkv, w_o, w_m1, w_m2, ws, id);
  else      transpose_body<false>(w_qkv, w_o, w_m1, w_m2, ws, id);
}

// ---------------- GEMM helpers ----------------
// A from LDS (wave-own rows), B from LDS Bt[n][ldb].
template <int NT, int KS>
__device__ __forceinline__ void gemm_tile(const bf16* sA, int lda,
                                          const bf16* sB, int ldb,
                                          f32x4* c, int w, int col, int quad) {
  const bf16* ap = sA + (w * 16 + col) * lda + quad * 8;
#pragma unroll
  for (int ks = 0; ks < KS; ++ks) {
    short8 a = *reinterpret_cast<const short8*>(ap + ks * 32);
#pragma unroll
    for (int nt = 0; nt < NT; ++nt) {
      short8 b = *reinterpret_cast<const short8*>(
          sB + (nt * 16 + col) * ldb + ks * 32 + quad * 8);
      c[nt] = __builtin_amdgcn_mfma_f32_16x16x32_bf16(a, b, c[nt], 0, 0, 0);
    }
  }
}

// A from LDS, B from GLOBAL Bt[n][ldk] (n-base pre-applied to gB). Full K.
// Reads gB[(nt*16+col)*ldk + ks*32 + quad*8 + j] -- element-identical to
// round 3's stage48-then-gemm_tile path.
template <int NT, int KS>
__device__ __forceinline__ void gemm_gB(const bf16* sA, int lda,
    const bf16* __restrict__ gB, int ldk, f32x4* c, int w, int col, int quad) {
  const bf16* ap = sA + (w * 16 + col) * lda + quad * 8;
  const bf16* bp = gB + col * ldk + quad * 8;
#pragma unroll
  for (int ks = 0; ks < KS; ++ks) {
    short8 a = *reinterpret_cast<const short8*>(ap + ks * 32);
#pragma unroll
    for (int nt = 0; nt < NT; ++nt) {
      short8 b = *reinterpret_cast<const short8*>(bp + nt * 16 * ldk + ks * 32);
      c[nt] = __builtin_amdgcn_mfma_f32_16x16x32_bf16(a, b, c[nt], 0, 0, 0);
    }
  }
}

// Same but K padded 48->64: memory positions >= 48 (ks==1 && quad>=2) use
// B=0 -- position-identical to round 3's stage96 zero-pad.
template <int NT>
__device__ __forceinline__ void gemm_gB_p48(const bf16* sA, int lda,
    const bf16* __restrict__ gB, int ldk, f32x4* c, int w, int col, int quad) {
  const bf16* ap = sA + (w * 16 + col) * lda + quad * 8;
  const bf16* bp = gB + col * ldk + quad * 8;
#pragma unroll
  for (int ks = 0; ks < 2; ++ks) {
    short8 a = *reinterpret_cast<const short8*>(ap + ks * 32);
#pragma unroll
    for (int nt = 0; nt < NT; ++nt) {
      short8 b = {0, 0, 0, 0, 0, 0, 0, 0};
      if (ks == 0 || quad < 2)
        b = *reinterpret_cast<const short8*>(bp + nt * 16 * ldk + ks * 32);
      c[nt] = __builtin_amdgcn_mfma_f32_16x16x32_bf16(a, b, c[nt], 0, 0, 0);
    }
  }
}

// ---------------- main fused kernel ----------------
template <bool ISBF>
__device__ void swin_mfma_body(
    const void* __restrict__ x,
    const void* __restrict__ g1, const void* __restrict__ b1,
    const void* __restrict__ b_qkv, const void* __restrict__ b_o,
    const void* __restrict__ g2, const void* __restrict__ b2,
    const void* __restrict__ b_m1, const void* __restrict__ b_m2,
    const bf16* __restrict__ ws, void* __restrict__ out, char* smem)
{
  bf16* sX = reinterpret_cast<bf16*>(smem);             // [64][200]
  bf16* sQ = reinterpret_cast<bf16*>(smem + 25600);     // [64][72] Q, then Oh
  bf16* sK = reinterpret_cast<bf16*>(smem + 34816);     // [64][72] K, then Hc
  bf16* sV = reinterpret_cast<bf16*>(smem + 44032);     // [48][72]
  bf16* sP = reinterpret_cast<bf16*>(smem + 50944);     // [64][72]
  float* red = reinterpret_cast<float*>(smem + 50944);  // LN1 scratch (=sP)

  const bf16* wsq  = ws;
  const bf16* wso  = ws + 110592;
  const bf16* wsm1 = ws + 147456;
  const bf16* wsm2 = ws + 294912;

  const int wi = blockIdx.x;
  const int bb = wi >> 10, hy = (wi >> 5) & 31, wx = wi & 31;
  const int tid = threadIdx.x;
  const int w = tid >> 6, lane = tid & 63, col = lane & 15, quad = lane >> 4;
  const int t = tid >> 2, qq = tid & 3;
  const int ty = t >> 3, tx = t & 7;
  const int ph = (hy * 8 + ty + 4) & 255;
  const int pw = (wx * 8 + tx + 4) & 255;

  // zero k-pad cols 48..63 of sQ and sK (persist: GEMMs write only 0..47)
  {
    int buf = tid >> 7, rh = tid & 127, row = rh >> 1, half = rh & 1;
    short8 z = {0, 0, 0, 0, 0, 0, 0, 0};
    *reinterpret_cast<short8*>((buf ? sK : sQ) + row * 72 + 48 + half * 8) = z;
  }

  // ---- load window + LN1 (thread (t,qq) owns token t, channels qq*48..) ----
  {
    const size_t xb = (((size_t)(bb * 192 + qq * 48)) << 16) + (ph << 8) + pw;
    float s = 0.f, ss = 0.f;
    for (int j = 0; j < 48; ++j) {
      float v = gldf<ISBF>(x, xb + ((size_t)j << 16));
      s += v; ss += v * v;
      sX[t * 200 + qq * 48 + j] = f2b(v);
    }
    red[(t * 4 + qq) * 2 + 0] = s;
    red[(t * 4 + qq) * 2 + 1] = ss;
  }
  __syncthreads();
  {
    float s = 0.f, ss = 0.f;
    for (int k = 0; k < 4; ++k) {
      s  += red[(t * 4 + k) * 2 + 0];
      ss += red[(t * 4 + k) * 2 + 1];
    }
    float mu  = s * (1.f / 192.f);
    float var = ss * (1.f / 192.f) - mu * mu;
    float inv = rsqrtf(var + 1e-5f);
    for (int j = 0; j < 48; ++j) {
      int c = qq * 48 + j;
      float v = b2f(sX[t * 200 + c]);
      sX[t * 200 + c] =
          f2b((v - mu) * inv * gldf<ISBF>(g1, c) + gldf<ISBF>(b1, c));
    }
  }
  __syncthreads();   // LN1 -> GEMM A-reads

  // ---- attention ----
  f32x4 accW[12];
#pragma unroll
  for (int i = 0; i < 12; ++i) accW[i] = {0.f, 0.f, 0.f, 0.f};
  const float scale = 0.14433756729740643f;   // 1/sqrt(48)

  for (int h = 0; h < 4; ++h) {
    if (h) __syncthreads();     // WAR: prev-head sK/sV reads -> new writes
    // Q projection -> sQ (own rows; pad stays zero)
    {
      f32x4 c3[3] = {{0,0,0,0},{0,0,0,0},{0,0,0,0}};
      gemm_gB<3, 6>(sX, 200, wsq + (size_t)(h * 48) * 192, 192, c3, w, col, quad);
#pragma unroll
      for (int nt = 0; nt < 3; ++nt) {
        float bq = gldf<ISBF>(b_qkv, h * 48 + nt * 16 + col);
#pragma unroll
        for (int r = 0; r < 4; ++r)
          sQ[(w * 16 + quad * 4 + r) * 72 + nt * 16 + col] =
              f2b((c3[nt][r] + bq) * scale);
      }
    }
    // K projection -> sK (own rows; pad stays zero)
    {
      f32x4 c3[3] = {{0,0,0,0},{0,0,0,0},{0,0,0,0}};
      gemm_gB<3, 6>(sX, 200, wsq + (size_t)(192 + h * 48) * 192, 192, c3, w, col, quad);
#pragma unroll
      for (int nt = 0; nt < 3; ++nt) {
        float bk = gldf<ISBF>(b_qkv, 192 + h * 48 + nt * 16 + col);
#pragma unroll
        for (int r = 0; r < 4; ++r)
          sK[(w * 16 + quad * 4 + r) * 72 + nt * 16 + col] = f2b(c3[nt][r] + bk);
      }
    }
    // V projection -> sV transposed [d][token]
    {
      f32x4 c3[3] = {{0,0,0,0},{0,0,0,0},{0,0,0,0}};
      gemm_gB<3, 6>(sX, 200, wsq + (size_t)(384 + h * 48) * 192, 192, c3, w, col, quad);
#pragma unroll
      for (int nt = 0; nt < 3; ++nt) {
        float bv = gldf<ISBF>(b_qkv, 384 + h * 48 + nt * 16 + col);
#pragma unroll
        for (int r = 0; r < 4; ++r)
          sV[(nt * 16 + col) * 72 + w * 16 + quad * 4 + r] = f2b(c3[nt][r] + bv);
      }
    }
    __syncthreads();   // Q/K/V visible to all waves

    // S = Q K^T (K=64 incl. zero pad), softmax in C-layout registers
    {
      f32x4 s4[4] = {{0,0,0,0},{0,0,0,0},{0,0,0,0},{0,0,0,0}};
      gemm_tile<4, 2>(sQ, 72, sK, 72, s4, w, col, quad);
      float inv[4];
#pragma unroll
      for (int r = 0; r < 4; ++r) {
        float m = fmaxf(fmaxf(s4[0][r], s4[1][r]), fmaxf(s4[2][r], s4[3][r]));
#pragma unroll
        for (int msk = 1; msk < 16; msk <<= 1) m = fmaxf(m, __shfl_xor(m, msk, 64));
        float sum = 0.f;
#pragma unroll
        for (int nt = 0; nt < 4; ++nt) {
          float e = expf(s4[nt][r] - m);
          s4[nt][r] = e; sum += e;
        }
#pragma unroll
        for (int msk = 1; msk < 16; msk <<= 1) sum += __shfl_xor(sum, msk, 64);
        inv[r] = 1.f / sum;
      }
#pragma unroll
      for (int nt = 0; nt < 4; ++nt)
#pragma unroll
        for (int r = 0; r < 4; ++r)
          sP[(w * 16 + quad * 4 + r) * 72 + nt * 16 + col] =
              f2b(s4[nt][r] * inv[r]);
    }
    __syncthreads();   // P ordered/visible before PV A-reads

    // PV (K=64 tokens) -> Oh over sQ cols 0..47 (pad cols still zero)
    {
      f32x4 c3[3] = {{0,0,0,0},{0,0,0,0},{0,0,0,0}};
      gemm_tile<3, 2>(sP, 72, sV, 72, c3, w, col, quad);
#pragma unroll
      for (int nt = 0; nt < 3; ++nt)
#pragma unroll
        for (int r = 0; r < 4; ++r)
          sQ[(w * 16 + quad * 4 + r) * 72 + nt * 16 + col] = f2b(c3[nt][r]);
    }
    __syncthreads();   // Oh ordered/visible before o_proj A-reads

    // o_proj partial: accW += Oh @ WoT[h-slice], two 96-wide n-strips
    gemm_gB_p48<6>(sQ, 72, wso + (size_t)(0 * 96) * 192 + h * 48, 192,
                   accW + 0, w, col, quad);
    gemm_gB_p48<6>(sQ, 72, wso + (size_t)(1 * 96) * 192 + h * 48, 192,
                   accW + 6, w, col, quad);
  }
  __syncthreads();   // all attention reads of sK/sV done; Hc overlay safe

  // ---- epilogue: w2 = LN1out + attn + b_o ; LN2 -> sX ; accW += b_m2 ----
  {
#pragma unroll
    for (int nt = 0; nt < 12; ++nt) {
      int c = nt * 16 + col;
      float bo = gldf<ISBF>(b_o, c);
#pragma unroll
      for (int r = 0; r < 4; ++r)
        accW[nt][r] += bo + b2f(sX[(w * 16 + quad * 4 + r) * 200 + c]);
    }
    float su[4] = {0,0,0,0}, sq[4] = {0,0,0,0};
#pragma unroll
    for (int nt = 0; nt < 12; ++nt)
#pragma unroll
      for (int r = 0; r < 4; ++r) {
        su[r] += accW[nt][r]; sq[r] += accW[nt][r] * accW[nt][r];
      }
#pragma unroll
    for (int r = 0; r < 4; ++r) {
#pragma unroll
      for (int msk = 1; msk < 16; msk <<= 1) {
        su[r] += __shfl_xor(su[r], msk, 64);
        sq[r] += __shfl_xor(sq[r], msk, 64);
      }
    }
    float mu[4], inv[4];
#pragma unroll
    for (int r = 0; r < 4; ++r) {
      mu[r] = su[r] * (1.f / 192.f);
      inv[r] = rsqrtf(sq[r] * (1.f / 192.f) - mu[r] * mu[r] + 1e-5f);
    }
#pragma unroll
    for (int nt = 0; nt < 12; ++nt) {
      int c = nt * 16 + col;
      float g2c = gldf<ISBF>(g2, c), b2c = gldf<ISBF>(b2, c);
      float bm2 = gldf<ISBF>(b_m2, c);
#pragma unroll
      for (int r = 0; r < 4; ++r) {
        float hv = (accW[nt][r] - mu[r]) * inv[r] * g2c + b2c;
        sX[(w * 16 + quad * 4 + r) * 200 + c] = f2b(hv);   // sH over sX
        accW[nt][r] += bm2;
      }
    }
  }
  __syncthreads();   // LN2 -> MLP A-reads

  // ---- MLP: 16 chunks of 48 hidden units ----
  for (int ch = 0; ch < 16; ++ch) {
    {
      f32x4 c3[3] = {{0,0,0,0},{0,0,0,0},{0,0,0,0}};
      gemm_gB<3, 6>(sX, 200, wsm1 + (size_t)(ch * 48) * 192, 192, c3, w, col, quad);
#pragma unroll
      for (int nt = 0; nt < 3; ++nt) {
        float bm1 = gldf<ISBF>(b_m1, ch * 48 + nt * 16 + col);
#pragma unroll
        for (int r = 0; r < 4; ++r) {
          float v = c3[nt][r] + bm1;
          v = 0.5f * v * (1.f + erff(v * 0.70710678118654752f));
          sK[(w * 16 + quad * 4 + r) * 72 + nt * 16 + col] = f2b(v);  // Hc
        }
      }
    }
    __syncthreads();   // Hc ordered/visible before MLP2 A-reads
    gemm_gB_p48<6>(sK, 72, wsm2 + (size_t)(0 * 96) * 768 + ch * 48, 768,
                   accW + 0, w, col, quad);
    gemm_gB_p48<6>(sK, 72, wsm2 + (size_t)(1 * 96) * 768 + ch * 48, 768,
                   accW + 6, w, col, quad);
  }

  // ---- write w2 to LDS, then store (round-3 pattern) ----
  __syncthreads();
#pragma unroll
  for (int nt = 0; nt < 12; ++nt)
#pragma unroll
    for (int r = 0; r < 4; ++r)
      sX[(w * 16 + quad * 4 + r) * 200 + nt * 16 + col] = f2b(accW[nt][r]);
  __syncthreads();
  {
    const size_t ob = (((size_t)(bb * 192 + qq * 48)) << 16) + (ph << 8) + pw;
    for (int j = 0; j < 48; ++j)
      gst<ISBF>(out, ob + ((size_t)j << 16), b2f(sX[t * 200 + qq * 48 + j]));
  }
}

__global__ __launch_bounds__(256, 2) void swin_mfma(
    const void* x, const void* g1, const void* b1, const void* b_qkv,
    const void* b_o, const void* g2, const void* b2, const void* b_m1,
    const void* b_m2, const bf16* ws, void* out, int isbf)
{
  __shared__ __align__(16) char smem[60160];
  if (isbf)
    swin_mfma_body<true >(x, g1, b1, b_qkv, b_o, g2, b2, b_m1, b_m2, ws, out, smem);
  else
    swin_mfma_body<false>(x, g1, b1, b_qkv, b_o, g2, b2, b_m1, b_m2, ws, out, smem);
}

// ================= round-1 scalar fallback (ws too small) =================
template <bool ISBF>
__device__ __forceinline__ void gld4(const void* p, size_t i, float* o) {
  if constexpr (ISBF) {
    uint2 u = *reinterpret_cast<const uint2*>((const bf16*)p + i);
    union { unsigned int b; float f; } a;
    a.b = u.x << 16;          o[0] = a.f;
    a.b = u.x & 0xffff0000u;  o[1] = a.f;
    a.b = u.y << 16;          o[2] = a.f;
    a.b = u.y & 0xffff0000u;  o[3] = a.f;
  } else {
    float4 f = *reinterpret_cast<const float4*>((const float*)p + i);
    o[0] = f.x; o[1] = f.y; o[2] = f.z; o[3] = f.w;
  }
}

template <bool ISBF>
__device__ void swin_scalar_body(
    const void* x, const void* g1, const void* b1, const void* w_qkv,
    const void* b_qkv, const void* w_o, const void* b_o, const void* g2,
    const void* b2, const void* w_m1, const void* b_m1, const void* w_m2,
    const void* b_m2, void* out, bf16* s_w, char* s_buf)
{
  bf16*  sQ  = reinterpret_cast<bf16*>(s_buf);
  bf16*  sK  = reinterpret_cast<bf16*>(s_buf + 6400);
  bf16*  sV  = reinterpret_cast<bf16*>(s_buf + 12800);
  float* sS  = reinterpret_cast<float*>(s_buf + 19200);
  bf16*  sO  = sQ;
  bf16*  sH  = reinterpret_cast<bf16*>(s_buf);
  bf16*  sC  = reinterpret_cast<bf16*>(s_buf + 25600);
  float* red1 = reinterpret_cast<float*>(s_buf);
  float* red2 = reinterpret_cast<float*>(s_buf + 25600);

  const int wi = blockIdx.x;
  const int bb = wi >> 10, hy = (wi >> 5) & 31, wx = wi & 31;
  const int tid = threadIdx.x;
  const int t = tid >> 2, q = tid & 3;
  const int ty = t >> 3, tx = t & 7;
  const int ph = (hy * 8 + ty + 4) & 255, pw = (wx * 8 + tx + 4) & 255;
  float acc[48];
  {
    const size_t xb = (((size_t)(bb * 192 + q * 48)) << 16) + (ph << 8) + pw;
    float s = 0.f, ss = 0.f;
    for (int j = 0; j < 48; ++j) {
      float v = gldf<ISBF>(x, xb + ((size_t)j << 16));
      s += v; ss += v * v;
      s_w[t * 200 + q * 48 + j] = f2b(v);
    }
    red1[(t * 4 + q) * 2 + 0] = s; red1[(t * 4 + q) * 2 + 1] = ss;
  }
  __syncthreads();
  {
    float s = 0.f, ss = 0.f;
    for (int k = 0; k < 4; ++k) { s += red1[(t*4+k)*2]; ss += red1[(t*4+k)*2+1]; }
    float mu = s / 192.f, var = ss / 192.f - mu * mu, inv = rsqrtf(var + 1e-5f);
    for (int j = 0; j < 48; ++j) {
      int c = q * 48 + j;
      float v = (b2f(s_w[t*200+c]) - mu) * inv * gldf<ISBF>(g1,c) + gldf<ISBF>(b1,c);
      s_w[t * 200 + c] = f2b(v);
      acc[j] = v;
    }
  }
  __syncthreads();
  const float scale = 0.14433756729740643f;
  for (int h = 0; h < 4; ++h) {
    {
      float aq[12], ak[12], av[12];
      for (int j = 0; j < 12; ++j) {
        aq[j] = gldf<ISBF>(b_qkv, h*48 + q*12 + j);
        ak[j] = gldf<ISBF>(b_qkv, 192 + h*48 + q*12 + j);
        av[j] = gldf<ISBF>(b_qkv, 384 + h*48 + q*12 + j);
      }
      for (int c = 0; c < 192; ++c) {
        float a = b2f(s_w[t * 200 + c]);
        const size_t wr = (size_t)c * 576 + h * 48 + q * 12;
        float wv[4];
        for (int j0 = 0; j0 < 12; j0 += 4) {
          gld4<ISBF>(w_qkv, wr + j0, wv);
          for (int k = 0; k < 4; ++k) aq[j0+k] += a * wv[k];
        }
        for (int j0 = 0; j0 < 12; j0 += 4) {
          gld4<ISBF>(w_qkv, wr + 192 + j0, wv);
          for (int k = 0; k < 4; ++k) ak[j0+k] += a * wv[k];
        }
        for (int j0 = 0; j0 < 12; j0 += 4) {
          gld4<ISBF>(w_qkv, wr + 384 + j0, wv);
          for (int k = 0; k < 4; ++k) av[j0+k] += a * wv[k];
        }
      }
      for (int j = 0; j < 12; ++j) {
        sQ[t*50 + q*12 + j] = f2b(aq[j] * scale);
        sK[t*50 + q*12 + j] = f2b(ak[j]);
        sV[t*50 + q*12 + j] = f2b(av[j]);
      }
    }
    __syncthreads();
    {
      float as[16];
      for (int j = 0; j < 16; ++j) as[j] = 0.f;
      for (int d = 0; d < 48; ++d) {
        float qv = b2f(sQ[t*50 + d]);
        for (int j = 0; j < 16; ++j) as[j] += qv * b2f(sK[(q*16+j)*50 + d]);
      }
      for (int j = 0; j < 16; ++j) sS[t*66 + q*16 + j] = as[j];
    }
    __syncthreads();
    if (tid < 64) {
      float mx = -1e30f;
      for (int j = 0; j < 64; ++j) mx = fmaxf(mx, sS[tid*66+j]);
      float sum = 0.f;
      for (int j = 0; j < 64; ++j) { float e = expf(sS[tid*66+j]-mx); sS[tid*66+j]=e; sum+=e; }
      float r = 1.f / sum;
      for (int j = 0; j < 64; ++j) sS[tid*66+j] *= r;
    }
    __syncthreads();
    {
      float ao[12];
      for (int j = 0; j < 12; ++j) ao[j] = 0.f;
      for (int j = 0; j < 64; ++j) {
        float p = sS[t*66 + j];
        for (int k = 0; k < 12; ++k) ao[k] += p * b2f(sV[j*50 + q*12 + k]);
      }
      for (int j = 0; j < 12; ++j) sO[t*50 + q*12 + j] = f2b(ao[j]);
    }
    __syncthreads();
    for (int d = 0; d < 48; ++d) {
      float ov = b2f(sO[t*50 + d]);
      const size_t wr = (size_t)(h*48+d) * 192 + q * 48;
      float wv[4];
      for (int j0 = 0; j0 < 48; j0 += 4) {
        gld4<ISBF>(w_o, wr + j0, wv);
        for (int k = 0; k < 4; ++k) acc[j0+k] += ov * wv[k];
      }
    }
    __syncthreads();
  }
  for (int j = 0; j < 48; ++j) acc[j] += gldf<ISBF>(b_o, q*48 + j);
  {
    float s = 0.f, ss = 0.f;
    for (int j = 0; j < 48; ++j) { s += acc[j]; ss += acc[j]*acc[j]; }
    red2[(t*4+q)*2] = s; red2[(t*4+q)*2+1] = ss;
  }
  __syncthreads();
  {
    float s = 0.f, ss = 0.f;
    for (int k = 0; k < 4; ++k) { s += red2[(t*4+k)*2]; ss += red2[(t*4+k)*2+1]; }
    float mu = s/192.f, var = ss/192.f - mu*mu, inv = rsqrtf(var + 1e-5f);
    for (int j = 0; j < 48; ++j) {
      int c = q*48 + j;
      sH[t*200+c] = f2b((acc[j]-mu)*inv*gldf<ISBF>(g2,c) + gldf<ISBF>(b2,c));
    }
  }
  for (int j = 0; j < 48; ++j) acc[j] += gldf<ISBF>(b_m2, q*48 + j);
  __syncthreads();
  for (int ch = 0; ch < 8; ++ch) {
    float am[24];
    for (int j = 0; j < 24; ++j) am[j] = gldf<ISBF>(b_m1, ch*96 + q*24 + j);
    for (int c = 0; c < 192; ++c) {
      float hv = b2f(sH[t*200 + c]);
      const size_t wr = (size_t)c * 768 + ch*96 + q*24;
      float wv[4];
      for (int j0 = 0; j0 < 24; j0 += 4) {
        gld4<ISBF>(w_m1, wr + j0, wv);
        for (int k = 0; k < 4; ++k) am[j0+k] += hv * wv[k];
      }
    }
    for (int j = 0; j < 24; ++j) {
      float v = am[j];
      am[j] = 0.5f * v * (1.f + erff(v * 0.70710678118654752f));
    }
    for (int j = 0; j < 24; ++j) sC[t*104 + q*24 + j] = f2b(am[j]);
    __syncthreads();
    for (int u = 0; u < 96; ++u) {
      float hv = b2f(sC[t*104 + u]);
      const size_t wr = (size_t)(ch*96+u) * 192 + q*48;
      float wv[4];
      for (int j0 = 0; j0 < 48; j0 += 4) {
        gld4<ISBF>(w_m2, wr + j0, wv);
        for (int k = 0; k < 4; ++k) acc[j0+k] += hv * wv[k];
      }
    }
    __syncthreads();
  }
  {
    const size_t ob = (((size_t)(bb*192 + q*48)) << 16) + (ph << 8) + pw;
    for (int j = 0; j < 48; ++j) gst<ISBF>(out, ob + ((size_t)j << 16), acc[j]);
  }
}

__global__ __launch_bounds__(256) void swin_scalar(
    const void* x, const void* g1, const void* b1, const void* w_qkv,
    const void* b_qkv, const void* w_o, const void* b_o, const void* g2,
    const void* b2, const void* w_m1, const void* b_m1, const void* w_m2,
    const void* b_m2, void* out, int isbf)
{
  __shared__ bf16 s_w[64 * 200];
  __shared__ __align__(16) char s_buf[38912];
  if (isbf)
    swin_scalar_body<true >(x,g1,b1,w_qkv,b_qkv,w_o,b_o,g2,b2,w_m1,b_m1,w_m2,b_m2,out,s_w,s_buf);
  else
    swin_scalar_body<false>(x,g1,b1,w_qkv,b_qkv,w_o,b_o,g2,b2,w_m1,b_m1,w_m2,b_m2,out,s_w,s_buf);
}

extern "C" void kernel_launch(void* const* d_in, const int* in_sizes, int n_in,
                              void* d_out, int out_size, void* d_ws, size_t ws_size,
                              hipStream_t stream) {
  // Dtype from tensor byte-size (value-independent; robust to re-poisoning).
  // g1 has 192 elements: 768 B fp32, 384 B bf16.
  const int isbf = (n_in > 1 && in_sizes != nullptr && in_sizes[1] == 384) ? 1 : 0;
  if (ws_size >= 884736) {
    transpose_weights<<<dim3(1728), dim3(256), 0, stream>>>(
        d_in[3], d_in[5], d_in[9], d_in[11], (bf16*)d_ws, isbf);
    swin_mfma<<<dim3(4096), dim3(256), 0, stream>>>(
        d_in[0], d_in[1], d_in[2], d_in[4], d_in[6], d_in[7], d_in[8],
        d_in[10], d_in[12], (const bf16*)d_ws, d_out, isbf);
  } else {
    swin_scalar<<<dim3(4096), dim3(256), 0, stream>>>(
        d_in[0], d_in[1], d_in[2], d_in[3], d_in[4], d_in[5], d_in[6],
        d_in[7], d_in[8], d_in[9], d_in[10], d_in[11], d_in[12], d_out, isbf);
  }
}

// Round 6
// 1441.170 us; speedup vs baseline: 1.4971x; 1.4971x over previous
//
#include <hip/hip_runtime.h>
#include <hip/hip_bf16.h>
#include <cmath>

// SwinBlock fused kernel, round 8: round-3 verified per-window dataflow,
// TWO windows per 512-thread block in lockstep, sharing the sW weight tile.
// Staging is done once by all 512 threads and consumed by both windows ->
// staging traffic + barrier count per window halved, MFMA per barrier 2x.
// vec-I/O + shfl-LN1 dropped for good (3-strike bisect: r4/r5/r7 all fail
// ~0.23-0.28 with it; r3/r6 without it pass). Scalar I/O + LDS-red LN1 kept.
//
// LDS map (bytes, total 125184):
//   sW    @0      (19200, shared)   | sP0 @0 (alias), sP1 @9216 (alias)
//   sX0   @19200  sX1 @44800  (2 x 25600)
//   sQ0   @70400  sQ1 @79616  (2 x 9216)
//   sK0   @88832  sK1 @98048  (2 x 9216)   (later Hc)
//   sV0   @107264 sV1 @114176 (2 x 6912)
//   red0  @121088 red1 @123136 (2 x 2048)
// sP<->sW alias safety: last sW B-read (V-proj gemm) -> barrier -> sP writes;
// PV sP reads -> barrier -> o_proj stage96 sW writes. Lockstep block-wide
// barriers order both windows identically.

using bf16 = __hip_bfloat16;
typedef __attribute__((ext_vector_type(8))) short short8;
typedef __attribute__((ext_vector_type(4))) float f32x4;

__device__ __forceinline__ float b2f(bf16 v) { return __bfloat162float(v); }
__device__ __forceinline__ bf16  f2b(float v) { return __float2bfloat16(v); }

template <bool ISBF>
__device__ __forceinline__ float gldf(const void* p, size_t i) {
  if constexpr (ISBF) return b2f(((const bf16*)p)[i]);
  else                return ((const float*)p)[i];
}
template <bool ISBF>
__device__ __forceinline__ void gst(void* p, size_t i, float v) {
  if constexpr (ISBF) ((bf16*)p)[i] = f2b(v);
  else                ((float*)p)[i] = v;
}

// ---------------- weight pre-transpose into workspace ----------------
// ws layout (bf16 elements): qkvT[576][192] @0 ; oT[192][192] @110592 ;
// m1T[768][192] @147456 ; m2T[192][768] @294912. Total 442368 elems.
template <bool ISBF>
__device__ __forceinline__ void transpose_body(
    const void* w_qkv, const void* w_o, const void* w_m1, const void* w_m2,
    bf16* ws, int id)
{
  if (id < 110592) {                       // qkv: src [192][576]
    int n = id / 192, k = id - n * 192;
    ws[id] = f2b(gldf<ISBF>(w_qkv, (size_t)k * 576 + n));
  } else if (id < 147456) {                // o: src [192][192]
    int l = id - 110592;
    int n = l / 192, k = l - n * 192;
    ws[id] = f2b(gldf<ISBF>(w_o, (size_t)k * 192 + n));
  } else if (id < 294912) {                // m1: src [192][768]
    int l = id - 147456;
    int n = l / 192, k = l - n * 192;
    ws[id] = f2b(gldf<ISBF>(w_m1, (size_t)k * 768 + n));
  } else {                                 // m2: src [768][192]
    int l = id - 294912;
    int n = l / 768, k = l - n * 768;
    ws[id] = f2b(gldf<ISBF>(w_m2, (size_t)k * 192 + n));
  }
}

__global__ __launch_bounds__(256) void transpose_weights(
    const void* w_qkv, const void* w_o, const void* w_m1, const void* w_m2,
    bf16* ws, int isbf)
{
  int id = blockIdx.x * 256 + threadIdx.x;
  if (id >= 442368) return;
  if (isbf) transpose_body<true >(w_qkv, w_o, w_m1, w_m2, ws, id);
  else      transpose_body<false>(w_qkv, w_o, w_m1, w_m2, ws, id);
}

// ---------------- LDS staging helpers (512-thread versions) ----------------
// [48 rows][stride 200], src row stride 192, 24 x 16B per row.
__device__ __forceinline__ void stage48_512(bf16* dst, const bf16* src,
                                            int tid512) {
  for (int idx = tid512; idx < 1152; idx += 512) {
    int r = idx / 24, g = idx - r * 24;
    *reinterpret_cast<short8*>(dst + r * 200 + g * 8) =
        *reinterpret_cast<const short8*>(src + r * 192 + g * 8);
  }
}
// [96 rows][stride 72], k cols 0..47 from src (+kOff), 48..63 zero.
__device__ __forceinline__ void stage96_512(bf16* dst, const bf16* srcBase,
                                            int srcStride, int kOff,
                                            int tid512) {
  for (int i = 0; i < 2; ++i) {
    int idx = tid512 + i * 512;
    if (idx < 768) {
      int r = idx >> 3, g = idx & 7;
      short8 v = {0, 0, 0, 0, 0, 0, 0, 0};
      if (g < 6)
        v = *reinterpret_cast<const short8*>(srcBase + (size_t)r * srcStride +
                                             kOff + g * 8);
      *reinterpret_cast<short8*>(dst + r * 72 + g * 8) = v;
    }
  }
}

// GEMM: wave-local m-tile w (0..3 within the window); NT n-tiles, KS k-steps.
template <int NT, int KS>
__device__ __forceinline__ void gemm_tile(const bf16* sA, int lda,
                                          const bf16* sB, int ldb,
                                          f32x4* c, int w, int col, int quad) {
  const bf16* ap = sA + (w * 16 + col) * lda + quad * 8;
#pragma unroll
  for (int ks = 0; ks < KS; ++ks) {
    short8 a = *reinterpret_cast<const short8*>(ap + ks * 32);
#pragma unroll
    for (int nt = 0; nt < NT; ++nt) {
      short8 b = *reinterpret_cast<const short8*>(
          sB + (nt * 16 + col) * ldb + ks * 32 + quad * 8);
      c[nt] = __builtin_amdgcn_mfma_f32_16x16x32_bf16(a, b, c[nt], 0, 0, 0);
    }
  }
}

// ---------------- main fused kernel: 2 windows per 512-thread block --------
template <bool ISBF>
__device__ void swin_mfma_body(
    const void* __restrict__ x,
    const void* __restrict__ g1, const void* __restrict__ b1,
    const void* __restrict__ b_qkv, const void* __restrict__ b_o,
    const void* __restrict__ g2, const void* __restrict__ b2,
    const void* __restrict__ b_m1, const void* __restrict__ b_m2,
    const bf16* __restrict__ ws, void* __restrict__ out, char* smem)
{
  const int tid512 = threadIdx.x;        // 0..511
  const int wsel   = tid512 >> 8;        // window within block
  const int tid    = tid512 & 255;       // round-3 local tid

  bf16* sW  = reinterpret_cast<bf16*>(smem);                       // shared
  bf16* sP  = reinterpret_cast<bf16*>(smem + wsel * 9216);         // alias sW
  bf16* sX  = reinterpret_cast<bf16*>(smem + 19200 + wsel * 25600);
  bf16* sQ  = reinterpret_cast<bf16*>(smem + 70400 + wsel * 9216); // later Oh
  bf16* sK  = reinterpret_cast<bf16*>(smem + 88832 + wsel * 9216); // later Hc
  bf16* sV  = reinterpret_cast<bf16*>(smem + 107264 + wsel * 6912);
  float* red = reinterpret_cast<float*>(smem + 121088 + wsel * 2048);

  const bf16* wsq  = ws;
  const bf16* wso  = ws + 110592;
  const bf16* wsm1 = ws + 147456;
  const bf16* wsm2 = ws + 294912;

  const int wi = blockIdx.x * 2 + wsel;
  const int bb = wi >> 10, hy = (wi >> 5) & 31, wx = wi & 31;
  const int w = tid >> 6, lane = tid & 63, col = lane & 15, quad = lane >> 4;
  const int t = tid >> 2, qq = tid & 3;
  const int ty = t >> 3, tx = t & 7;
  const int ph = (hy * 8 + ty + 4) & 255;
  const int pw = (wx * 8 + tx + 4) & 255;

  // zero k-pad cols 48..63 of this window's sQ and sK (persist; all later
  // writes to sQ/sK touch cols 0..47 only)
  {
    int buf = tid >> 7, rh = tid & 127, row = rh >> 1, half = rh & 1;
    short8 z = {0, 0, 0, 0, 0, 0, 0, 0};
    *reinterpret_cast<short8*>((buf ? sK : sQ) + row * 72 + 48 + half * 8) = z;
  }

  // ---- load window + LN1 (thread (t,qq) owns token t, channels qq*48..) ----
  {
    const size_t xb = (((size_t)(bb * 192 + qq * 48)) << 16) + (ph << 8) + pw;
    float s = 0.f, ss = 0.f;
    for (int j = 0; j < 48; ++j) {
      float v = gldf<ISBF>(x, xb + ((size_t)j << 16));
      s += v; ss += v * v;
      sX[t * 200 + qq * 48 + j] = f2b(v);
    }
    red[(t * 4 + qq) * 2 + 0] = s;
    red[(t * 4 + qq) * 2 + 1] = ss;
  }
  __syncthreads();
  {
    float s = 0.f, ss = 0.f;
    for (int k = 0; k < 4; ++k) {
      s  += red[(t * 4 + k) * 2 + 0];
      ss += red[(t * 4 + k) * 2 + 1];
    }
    float mu  = s * (1.f / 192.f);
    float var = ss * (1.f / 192.f) - mu * mu;
    float inv = rsqrtf(var + 1e-5f);
    for (int j = 0; j < 48; ++j) {
      int c = qq * 48 + j;
      float v = b2f(sX[t * 200 + c]);
      sX[t * 200 + c] =
          f2b((v - mu) * inv * gldf<ISBF>(g1, c) + gldf<ISBF>(b1, c));
    }
  }

  // ---- attention ----
  f32x4 accW[12];
#pragma unroll
  for (int i = 0; i < 12; ++i) accW[i] = {0.f, 0.f, 0.f, 0.f};
  const float scale = 0.14433756729740643f;   // 1/sqrt(48)

  for (int h = 0; h < 4; ++h) {
    // Q projection (sW staged once, consumed by both windows)
    __syncthreads();
    stage48_512(sW, wsq + (size_t)(h * 48) * 192, tid512);
    __syncthreads();
    {
      f32x4 c3[3] = {{0,0,0,0},{0,0,0,0},{0,0,0,0}};
      gemm_tile<3, 6>(sX, 200, sW, 200, c3, w, col, quad);
#pragma unroll
      for (int nt = 0; nt < 3; ++nt) {
        float bq = gldf<ISBF>(b_qkv, h * 48 + nt * 16 + col);
#pragma unroll
        for (int r = 0; r < 4; ++r)
          sQ[(w * 16 + quad * 4 + r) * 72 + nt * 16 + col] =
              f2b((c3[nt][r] + bq) * scale);
      }
    }
    // K projection
    __syncthreads();
    stage48_512(sW, wsq + (size_t)(192 + h * 48) * 192, tid512);
    __syncthreads();
    {
      f32x4 c3[3] = {{0,0,0,0},{0,0,0,0},{0,0,0,0}};
      gemm_tile<3, 6>(sX, 200, sW, 200, c3, w, col, quad);
#pragma unroll
      for (int nt = 0; nt < 3; ++nt) {
        float bk = gldf<ISBF>(b_qkv, 192 + h * 48 + nt * 16 + col);
#pragma unroll
        for (int r = 0; r < 4; ++r)
          sK[(w * 16 + quad * 4 + r) * 72 + nt * 16 + col] = f2b(c3[nt][r] + bk);
      }
    }
    // V projection (store transposed: sV[d][token])
    __syncthreads();
    stage48_512(sW, wsq + (size_t)(384 + h * 48) * 192, tid512);
    __syncthreads();
    {
      f32x4 c3[3] = {{0,0,0,0},{0,0,0,0},{0,0,0,0}};
      gemm_tile<3, 6>(sX, 200, sW, 200, c3, w, col, quad);
#pragma unroll
      for (int nt = 0; nt < 3; ++nt) {
        float bv = gldf<ISBF>(b_qkv, 384 + h * 48 + nt * 16 + col);
#pragma unroll
        for (int r = 0; r < 4; ++r)
          sV[(nt * 16 + col) * 72 + w * 16 + quad * 4 + r] = f2b(c3[nt][r] + bv);
      }
    }
    __syncthreads();   // Qh/Kh/Vt visible; also orders last sW read -> sP use

    // S = Q K^T (K=64 incl. zero pad), softmax in C-layout registers
    {
      f32x4 s4[4] = {{0,0,0,0},{0,0,0,0},{0,0,0,0},{0,0,0,0}};
      gemm_tile<4, 2>(sQ, 72, sK, 72, s4, w, col, quad);
      float inv[4];
#pragma unroll
      for (int r = 0; r < 4; ++r) {
        float m = fmaxf(fmaxf(s4[0][r], s4[1][r]), fmaxf(s4[2][r], s4[3][r]));
#pragma unroll
        for (int msk = 1; msk < 16; msk <<= 1) m = fmaxf(m, __shfl_xor(m, msk, 64));
        float sum = 0.f;
#pragma unroll
        for (int nt = 0; nt < 4; ++nt) {
          float e = expf(s4[nt][r] - m);
          s4[nt][r] = e; sum += e;
        }
#pragma unroll
        for (int msk = 1; msk < 16; msk <<= 1) sum += __shfl_xor(sum, msk, 64);
        inv[r] = 1.f / sum;
      }
#pragma unroll
      for (int nt = 0; nt < 4; ++nt)
#pragma unroll
        for (int r = 0; r < 4; ++r)
          sP[(w * 16 + quad * 4 + r) * 72 + nt * 16 + col] =
              f2b(s4[nt][r] * inv[r]);
    }
    // PV (K=64 tokens): A = P (own rows just written, intra-wave ordered),
    // B = sV (stable since post-QKV barrier) -> Oh over sQ cols 0..47
    {
      f32x4 c3[3] = {{0,0,0,0},{0,0,0,0},{0,0,0,0}};
      gemm_tile<3, 2>(sP, 72, sV, 72, c3, w, col, quad);
#pragma unroll
      for (int nt = 0; nt < 3; ++nt)
#pragma unroll
        for (int r = 0; r < 4; ++r)
          sQ[(w * 16 + quad * 4 + r) * 72 + nt * 16 + col] = f2b(c3[nt][r]);
    }
    // o_proj partial: accW += Oh @ Wo[h-slice]^T, two 96-wide n-strips
    for (int s = 0; s < 2; ++s) {
      __syncthreads();           // PV sP reads done -> sW(=sP) overwrite OK
      stage96_512(sW, wso + (size_t)(s * 96) * 192, 192, h * 48, tid512);
      __syncthreads();
      gemm_tile<6, 2>(sQ, 72, sW, 72, accW + s * 6, w, col, quad);
    }
  }

  // ---- epilogue: w2 = LN1out + attn + b_o ; LN2 -> sH(=sX) ; += b_m2 ----
  {
#pragma unroll
    for (int nt = 0; nt < 12; ++nt) {
      int c = nt * 16 + col;
      float bo = gldf<ISBF>(b_o, c);
#pragma unroll
      for (int r = 0; r < 4; ++r)
        accW[nt][r] += bo + b2f(sX[(w * 16 + quad * 4 + r) * 200 + c]);
    }
    float su[4] = {0,0,0,0}, sq[4] = {0,0,0,0};
#pragma unroll
    for (int nt = 0; nt < 12; ++nt)
#pragma unroll
      for (int r = 0; r < 4; ++r) {
        su[r] += accW[nt][r]; sq[r] += accW[nt][r] * accW[nt][r];
      }
#pragma unroll
    for (int r = 0; r < 4; ++r) {
#pragma unroll
      for (int msk = 1; msk < 16; msk <<= 1) {
        su[r] += __shfl_xor(su[r], msk, 64);
        sq[r] += __shfl_xor(sq[r], msk, 64);
      }
    }
    float mu[4], inv[4];
#pragma unroll
    for (int r = 0; r < 4; ++r) {
      mu[r] = su[r] * (1.f / 192.f);
      inv[r] = rsqrtf(sq[r] * (1.f / 192.f) - mu[r] * mu[r] + 1e-5f);
    }
#pragma unroll
    for (int nt = 0; nt < 12; ++nt) {
      int c = nt * 16 + col;
      float g2c = gldf<ISBF>(g2, c), b2c = gldf<ISBF>(b2, c);
      float bm2 = gldf<ISBF>(b_m2, c);
#pragma unroll
      for (int r = 0; r < 4; ++r) {
        float hv = (accW[nt][r] - mu[r]) * inv[r] * g2c + b2c;
        sX[(w * 16 + quad * 4 + r) * 200 + c] = f2b(hv);   // sH over sX
        accW[nt][r] += bm2;
      }
    }
  }

  // ---- MLP: 16 chunks of 48 hidden units ----
  for (int ch = 0; ch < 16; ++ch) {
    __syncthreads();
    stage48_512(sW, wsm1 + (size_t)(ch * 48) * 192, tid512);
    __syncthreads();
    {
      f32x4 c3[3] = {{0,0,0,0},{0,0,0,0},{0,0,0,0}};
      gemm_tile<3, 6>(sX, 200, sW, 200, c3, w, col, quad);
#pragma unroll
      for (int nt = 0; nt < 3; ++nt) {
        float bm1 = gldf<ISBF>(b_m1, ch * 48 + nt * 16 + col);
#pragma unroll
        for (int r = 0; r < 4; ++r) {
          float v = c3[nt][r] + bm1;
          v = 0.5f * v * (1.f + erff(v * 0.70710678118654752f));
          sK[(w * 16 + quad * 4 + r) * 72 + nt * 16 + col] = f2b(v);  // Hc
        }
      }
    }
    for (int s = 0; s < 2; ++s) {
      __syncthreads();
      stage96_512(sW, wsm2 + (size_t)(s * 96) * 768, 768, ch * 48, tid512);
      __syncthreads();
      gemm_tile<6, 2>(sK, 72, sW, 72, accW + s * 6, w, col, quad);
    }
  }

  // ---- write w2 to LDS, then store (round-3 pattern) ----
  __syncthreads();
#pragma unroll
  for (int nt = 0; nt < 12; ++nt)
#pragma unroll
    for (int r = 0; r < 4; ++r)
      sX[(w * 16 + quad * 4 + r) * 200 + nt * 16 + col] = f2b(accW[nt][r]);
  __syncthreads();
  {
    const size_t ob = (((size_t)(bb * 192 + qq * 48)) << 16) + (ph << 8) + pw;
    for (int j = 0; j < 48; ++j)
      gst<ISBF>(out, ob + ((size_t)j << 16), b2f(sX[t * 200 + qq * 48 + j]));
  }
}

__global__ __launch_bounds__(512, 1) void swin_mfma(
    const void* x, const void* g1, const void* b1, const void* b_qkv,
    const void* b_o, const void* g2, const void* b2, const void* b_m1,
    const void* b_m2, const bf16* ws, void* out, int isbf)
{
  __shared__ __align__(16) char smem[125184];
  if (isbf)
    swin_mfma_body<true >(x, g1, b1, b_qkv, b_o, g2, b2, b_m1, b_m2, ws, out, smem);
  else
    swin_mfma_body<false>(x, g1, b1, b_qkv, b_o, g2, b2, b_m1, b_m2, ws, out, smem);
}

// ================= round-1 scalar fallback (ws too small) =================
template <bool ISBF>
__device__ __forceinline__ void gld4(const void* p, size_t i, float* o) {
  if constexpr (ISBF) {
    uint2 u = *reinterpret_cast<const uint2*>((const bf16*)p + i);
    union { unsigned int b; float f; } a;
    a.b = u.x << 16;          o[0] = a.f;
    a.b = u.x & 0xffff0000u;  o[1] = a.f;
    a.b = u.y << 16;          o[2] = a.f;
    a.b = u.y & 0xffff0000u;  o[3] = a.f;
  } else {
    float4 f = *reinterpret_cast<const float4*>((const float*)p + i);
    o[0] = f.x; o[1] = f.y; o[2] = f.z; o[3] = f.w;
  }
}

template <bool ISBF>
__device__ void swin_scalar_body(
    const void* x, const void* g1, const void* b1, const void* w_qkv,
    const void* b_qkv, const void* w_o, const void* b_o, const void* g2,
    const void* b2, const void* w_m1, const void* b_m1, const void* w_m2,
    const void* b_m2, void* out, bf16* s_w, char* s_buf)
{
  bf16*  sQ  = reinterpret_cast<bf16*>(s_buf);
  bf16*  sK  = reinterpret_cast<bf16*>(s_buf + 6400);
  bf16*  sV  = reinterpret_cast<bf16*>(s_buf + 12800);
  float* sS  = reinterpret_cast<float*>(s_buf + 19200);
  bf16*  sO  = sQ;
  bf16*  sH  = reinterpret_cast<bf16*>(s_buf);
  bf16*  sC  = reinterpret_cast<bf16*>(s_buf + 25600);
  float* red1 = reinterpret_cast<float*>(s_buf);
  float* red2 = reinterpret_cast<float*>(s_buf + 25600);

  const int wi = blockIdx.x;
  const int bb = wi >> 10, hy = (wi >> 5) & 31, wx = wi & 31;
  const int tid = threadIdx.x;
  const int t = tid >> 2, q = tid & 3;
  const int ty = t >> 3, tx = t & 7;
  const int ph = (hy * 8 + ty + 4) & 255, pw = (wx * 8 + tx + 4) & 255;
  float acc[48];
  {
    const size_t xb = (((size_t)(bb * 192 + q * 48)) << 16) + (ph << 8) + pw;
    float s = 0.f, ss = 0.f;
    for (int j = 0; j < 48; ++j) {
      float v = gldf<ISBF>(x, xb + ((size_t)j << 16));
      s += v; ss += v * v;
      s_w[t * 200 + q * 48 + j] = f2b(v);
    }
    red1[(t * 4 + q) * 2 + 0] = s; red1[(t * 4 + q) * 2 + 1] = ss;
  }
  __syncthreads();
  {
    float s = 0.f, ss = 0.f;
    for (int k = 0; k < 4; ++k) { s += red1[(t*4+k)*2]; ss += red1[(t*4+k)*2+1]; }
    float mu = s / 192.f, var = ss / 192.f - mu * mu, inv = rsqrtf(var + 1e-5f);
    for (int j = 0; j < 48; ++j) {
      int c = q * 48 + j;
      float v = (b2f(s_w[t*200+c]) - mu) * inv * gldf<ISBF>(g1,c) + gldf<ISBF>(b1,c);
      s_w[t * 200 + c] = f2b(v);
      acc[j] = v;
    }
  }
  __syncthreads();
  const float scale = 0.14433756729740643f;
  for (int h = 0; h < 4; ++h) {
    {
      float aq[12], ak[12], av[12];
      for (int j = 0; j < 12; ++j) {
        aq[j] = gldf<ISBF>(b_qkv, h*48 + q*12 + j);
        ak[j] = gldf<ISBF>(b_qkv, 192 + h*48 + q*12 + j);
        av[j] = gldf<ISBF>(b_qkv, 384 + h*48 + q*12 + j);
      }
      for (int c = 0; c < 192; ++c) {
        float a = b2f(s_w[t * 200 + c]);
        const size_t wr = (size_t)c * 576 + h * 48 + q * 12;
        float wv[4];
        for (int j0 = 0; j0 < 12; j0 += 4) {
          gld4<ISBF>(w_qkv, wr + j0, wv);
          for (int k = 0; k < 4; ++k) aq[j0+k] += a * wv[k];
        }
        for (int j0 = 0; j0 < 12; j0 += 4) {
          gld4<ISBF>(w_qkv, wr + 192 + j0, wv);
          for (int k = 0; k < 4; ++k) ak[j0+k] += a * wv[k];
        }
        for (int j0 = 0; j0 < 12; j0 += 4) {
          gld4<ISBF>(w_qkv, wr + 384 + j0, wv);
          for (int k = 0; k < 4; ++k) av[j0+k] += a * wv[k];
        }
      }
      for (int j = 0; j < 12; ++j) {
        sQ[t*50 + q*12 + j] = f2b(aq[j] * scale);
        sK[t*50 + q*12 + j] = f2b(ak[j]);
        sV[t*50 + q*12 + j] = f2b(av[j]);
      }
    }
    __syncthreads();
    {
      float as[16];
      for (int j = 0; j < 16; ++j) as[j] = 0.f;
      for (int d = 0; d < 48; ++d) {
        float qv = b2f(sQ[t*50 + d]);
        for (int j = 0; j < 16; ++j) as[j] += qv * b2f(sK[(q*16+j)*50 + d]);
      }
      for (int j = 0; j < 16; ++j) sS[t*66 + q*16 + j] = as[j];
    }
    __syncthreads();
    if (tid < 64) {
      float mx = -1e30f;
      for (int j = 0; j < 64; ++j) mx = fmaxf(mx, sS[tid*66+j]);
      float sum = 0.f;
      for (int j = 0; j < 64; ++j) { float e = expf(sS[tid*66+j]-mx); sS[tid*66+j]=e; sum+=e; }
      float r = 1.f / sum;
      for (int j = 0; j < 64; ++j) sS[tid*66+j] *= r;
    }
    __syncthreads();
    {
      float ao[12];
      for (int j = 0; j < 12; ++j) ao[j] = 0.f;
      for (int j = 0; j < 64; ++j) {
        float p = sS[t*66 + j];
        for (int k = 0; k < 12; ++k) ao[k] += p * b2f(sV[j*50 + q*12 + k]);
      }
      for (int j = 0; j < 12; ++j) sO[t*50 + q*12 + j] = f2b(ao[j]);
    }
    __syncthreads();
    for (int d = 0; d < 48; ++d) {
      float ov = b2f(sO[t*50 + d]);
      const size_t wr = (size_t)(h*48+d) * 192 + q * 48;
      float wv[4];
      for (int j0 = 0; j0 < 48; j0 += 4) {
        gld4<ISBF>(w_o, wr + j0, wv);
        for (int k = 0; k < 4; ++k) acc[j0+k] += ov * wv[k];
      }
    }
    __syncthreads();
  }
  for (int j = 0; j < 48; ++j) acc[j] += gldf<ISBF>(b_o, q*48 + j);
  {
    float s = 0.f, ss = 0.f;
    for (int j = 0; j < 48; ++j) { s += acc[j]; ss += acc[j]*acc[j]; }
    red2[(t*4+q)*2] = s; red2[(t*4+q)*2+1] = ss;
  }
  __syncthreads();
  {
    float s = 0.f, ss = 0.f;
    for (int k = 0; k < 4; ++k) { s += red2[(t*4+k)*2]; ss += red2[(t*4+k)*2+1]; }
    float mu = s/192.f, var = ss/192.f - mu*mu, inv = rsqrtf(var + 1e-5f);
    for (int j = 0; j < 48; ++j) {
      int c = q*48 + j;
      sH[t*200+c] = f2b((acc[j]-mu)*inv*gldf<ISBF>(g2,c) + gldf<ISBF>(b2,c));
    }
  }
  for (int j = 0; j < 48; ++j) acc[j] += gldf<ISBF>(b_m2, q*48 + j);
  __syncthreads();
  for (int ch = 0; ch < 8; ++ch) {
    float am[24];
    for (int j = 0; j < 24; ++j) am[j] = gldf<ISBF>(b_m1, ch*96 + q*24 + j);
    for (int c = 0; c < 192; ++c) {
      float hv = b2f(sH[t*200 + c]);
      const size_t wr = (size_t)c * 768 + ch*96 + q*24;
      float wv[4];
      for (int j0 = 0; j0 < 24; j0 += 4) {
        gld4<ISBF>(w_m1, wr + j0, wv);
        for (int k = 0; k < 4; ++k) am[j0+k] += hv * wv[k];
      }
    }
    for (int j = 0; j < 24; ++j) {
      float v = am[j];
      am[j] = 0.5f * v * (1.f + erff(v * 0.70710678118654752f));
    }
    for (int j = 0; j < 24; ++j) sC[t*104 + q*24 + j] = f2b(am[j]);
    __syncthreads();
    for (int u = 0; u < 96; ++u) {
      float hv = b2f(sC[t*104 + u]);
      const size_t wr = (size_t)(ch*96+u) * 192 + q*48;
      float wv[4];
      for (int j0 = 0; j0 < 48; j0 += 4) {
        gld4<ISBF>(w_m2, wr + j0, wv);
        for (int k = 0; k < 4; ++k) acc[j0+k] += hv * wv[k];
      }
    }
    __syncthreads();
  }
  {
    const size_t ob = (((size_t)(bb*192 + q*48)) << 16) + (ph << 8) + pw;
    for (int j = 0; j < 48; ++j) gst<ISBF>(out, ob + ((size_t)j << 16), acc[j]);
  }
}

__global__ __launch_bounds__(256) void swin_scalar(
    const void* x, const void* g1, const void* b1, const void* w_qkv,
    const void* b_qkv, const void* w_o, const void* b_o, const void* g2,
    const void* b2, const void* w_m1, const void* b_m1, const void* w_m2,
    const void* b_m2, void* out, int isbf)
{
  __shared__ bf16 s_w[64 * 200];
  __shared__ __align__(16) char s_buf[38912];
  if (isbf)
    swin_scalar_body<true >(x,g1,b1,w_qkv,b_qkv,w_o,b_o,g2,b2,w_m1,b_m1,w_m2,b_m2,out,s_w,s_buf);
  else
    swin_scalar_body<false>(x,g1,b1,w_qkv,b_qkv,w_o,b_o,g2,b2,w_m1,b_m1,w_m2,b_m2,out,s_w,s_buf);
}

extern "C" void kernel_launch(void* const* d_in, const int* in_sizes, int n_in,
                              void* d_out, int out_size, void* d_ws, size_t ws_size,
                              hipStream_t stream) {
  // Dtype from tensor byte-size (value-independent; robust to re-poisoning).
  // g1 has 192 elements: 768 B fp32, 384 B bf16.
  const int isbf = (n_in > 1 && in_sizes != nullptr && in_sizes[1] == 384) ? 1 : 0;
  if (ws_size >= 884736) {
    transpose_weights<<<dim3(1728), dim3(256), 0, stream>>>(
        d_in[3], d_in[5], d_in[9], d_in[11], (bf16*)d_ws, isbf);
    swin_mfma<<<dim3(2048), dim3(512), 0, stream>>>(
        d_in[0], d_in[1], d_in[2], d_in[4], d_in[6], d_in[7], d_in[8],
        d_in[10], d_in[12], (const bf16*)d_ws, d_out, isbf);
  } else {
    swin_scalar<<<dim3(4096), dim3(256), 0, stream>>>(
        d_in[0], d_in[1], d_in[2], d_in[3], d_in[4], d_in[5], d_in[6],
        d_in[7], d_in[8], d_in[9], d_in[10], d_in[11], d_in[12], d_out, isbf);
  }
}